// Round 19
// baseline (8485.836 us; speedup 1.0000x reference)
//
#include <hip/hip_runtime.h>

#define T_DIM 512
#define B_DIM 64
#define H_DIM 1024
#define NBLK 32                // column blocks of 32 cols
#define RING 64                // h-state ring depth
#define KSLOT 33               // padded ks capacity: set-decorrelated weight stride
#define APITCH 1032            // A-frag row pitch in ushorts (2064B)
#define FSTR 1024              // flag stride in u32 (4KB)

typedef __attribute__((ext_vector_type(8))) short bf16x8;
typedef __attribute__((ext_vector_type(4))) float f32x4;

__device__ __forceinline__ unsigned short f2bf(float f) {
    unsigned u = __float_as_uint(f);
    unsigned r = (u + 0x7FFFu + ((u >> 16) & 1u)) >> 16;   // RNE
    return (unsigned short)r;
}
__device__ __forceinline__ unsigned pack2(float a, float b) {
    return (unsigned)f2bf(a) | ((unsigned)f2bf(b) << 16);
}

// ---------------- prep: pack weights into per-(block,jtile) MFMA B-fragment order --------
__global__ __launch_bounds__(128) void prep_pack(
    const float* __restrict__ Wir, const float* __restrict__ Wiz, const float* __restrict__ Win,
    const float* __restrict__ Whr, const float* __restrict__ Whz, const float* __restrict__ Whn,
    unsigned short* __restrict__ Wpk)
{
    const float* srcs[6] = {Wir, Wiz, Win, Whr, Whz, Whn};
    const int bid   = blockIdx.x;            // jt*64 + jtile*32 + ksrel
    const int g     = blockIdx.y;
    const int jt    = bid >> 6;
    const int jtile = (bid >> 5) & 1;
    const int ksrel = bid & 31;
    if (ksrel >= NBLK - jt) return;
    const int t    = threadIdx.x;
    const int lane = t >> 1, e0 = (t & 1) * 4;
    const float* src = srcs[g];
    const int j  = 32 * jt + 16 * jtile + (lane & 15);
    const int kb = (jt + ksrel) * 32 + (lane >> 4) * 8 + e0;
    ushort4 o; unsigned short* po = (unsigned short*)&o;
    #pragma unroll
    for (int i = 0; i < 4; ++i) {
        const int k = kb + i;
        const float w = (k >= j) ? src[(size_t)k * H_DIM + j] : 0.0f;
        po[i] = f2bf(w);
    }
    const size_t idx = ((((size_t)(jt * 2 + jtile) * KSLOT + ksrel) * 6 + g) * 64 + lane) * 8 + e0;
    *(ushort4*)(Wpk + idx) = o;
}

// ---------------- init: h0 -> ring slot 0 (bf16); zero progress flags ----------------
__global__ __launch_bounds__(256) void init_h(const float* __restrict__ h0,
                                              unsigned short* __restrict__ hring,
                                              unsigned* __restrict__ prog)
{
    if (blockIdx.x < 256) {
        const int i = blockIdx.x * 256 + threadIdx.x;   // B*H = 65536
        hring[i] = f2bf(h0[i]);
    } else {
        unsigned* p = prog + (size_t)(blockIdx.x - 256) * 8192 + threadIdx.x;
        #pragma unroll
        for (int k = 0; k < 32; ++k) p[k * 256] = 0u;
    }
}

// ---------------- main body, templated: SYNC=1 real kernel, SYNC=0 free-run probe --------
template <int SYNC>
__global__ __launch_bounds__(512) void gru_kernel(
    const float* __restrict__ x,      // [T,B,H]
    const unsigned short* __restrict__ Wpk,
    const float* __restrict__ bir, const float* __restrict__ bhr,
    const float* __restrict__ biz, const float* __restrict__ bhz,
    const float* __restrict__ bin_, const float* __restrict__ bhn,
    const float* __restrict__ Wout, const float* __restrict__ bout,
    const float* __restrict__ h0,
    unsigned short* __restrict__ hring,  // [RING][B][H] bf16
    float* __restrict__ pmax,            // [T,B,32]
    unsigned* __restrict__ prog)         // [8][32] @ FSTR
{
    __shared__ __align__(16) unsigned short axf[8 * APITCH];
    __shared__ __align__(16) unsigned short ahf[8 * APITCH];
    __shared__ __align__(16) unsigned short zblk[8];
    __shared__ float red[8][6][64][4];
    __shared__ float hown[8][33];
    __shared__ unsigned short hb[8][32];

    const int tid  = threadIdx.x;
    const int lane = tid & 63;
    const int wv   = tid >> 6;

    const int jt = blockIdx.x & 31;
    const int bg = blockIdx.x >> 5;
    const int b0 = bg * 8;

    const int kcol0 = 32 * jt;
    const int CHN   = (H_DIM - kcol0) >> 3;
    const int cnt   = NBLK - jt;
    const int jtile = wv >> 2;
    const int ws4   = wv & 3;
    const int kpw   = (cnt + 3) >> 2;
    const int ks_s  = jt + ws4 * kpw;
    const int ks_e  = (ks_s + kpw < NBLK) ? (ks_s + kpw) : NBLK;

    const int row = lane & 15;
    const int kg  = lane >> 4;
    const unsigned short* pax = (row < 8) ? &axf[row * APITCH + kg * 8] : zblk;
    const unsigned short* pah = (row < 8) ? &ahf[row * APITCH + kg * 8] : zblk;
    const int astride = (row < 8) ? 32 : 0;
    const unsigned short* pw0 = Wpk + (size_t)(jt * 2 + jtile) * KSLOT * 3072 + lane * 8;

    const int ecol = tid & 31;
    const int eb   = tid >> 5;
    const int ej   = 32 * jt + ecol;
    float c_bir = 0, c_bhr = 0, c_biz = 0, c_bhz = 0, c_bin = 0, c_bhn = 0, c_wo = 0, bo = 0;
    if (tid < 256) {
        c_bir = bir[ej]; c_bhr = bhr[ej]; c_biz = biz[ej]; c_bhz = bhz[ej];
        c_bin = bin_[ej]; c_bhn = bhn[ej]; c_wo = Wout[ej]; bo = bout[0];
    }

    unsigned* myflag = prog + (size_t)((bg << 5) + jt) * FSTR;
    unsigned* pollp  = prog + (size_t)((bg << 5) + (lane & 31)) * FSTR;
    unsigned* bpflag = prog + (size_t)(bg << 5) * FSTR;

    if (tid < 8) zblk[tid] = 0;
    if (tid < 256) hown[eb][ecol] = h0[(size_t)(b0 + eb) * H_DIM + ej];
    {
        const float* src = x + (size_t)(b0 + wv) * H_DIM + kcol0;
        #pragma unroll
        for (int s = 0; s < 2; ++s) {
            const int c8 = lane + (s << 6);
            if (c8 < CHN) {
                const float4 v0 = *(const float4*)(src + c8 * 8);
                const float4 v1 = *(const float4*)(src + c8 * 8 + 4);
                uint4 o = make_uint4(pack2(v0.x, v0.y), pack2(v0.z, v0.w),
                                     pack2(v1.x, v1.y), pack2(v1.z, v1.w));
                *(uint4*)&axf[wv * APITCH + c8 * 8] = o;
            }
        }
    }

    unsigned cachedf  = 0;
    unsigned cachedbp = 0;

    for (int t = 0; t < T_DIM; ++t) {
        const int slot_r = t & (RING - 1), slot_w = (t + 1) & (RING - 1);

        if (SYNC) {
            if (wv == 0) {
                const int kt = lane & 31;
                const int thr = (kt > jt) ? t : -0x40000000;
                if (!__all((int)cachedf >= thr)) {
                    for (;;) {
                        cachedf = __hip_atomic_load(pollp, __ATOMIC_RELAXED,
                                                    __HIP_MEMORY_SCOPE_AGENT);
                        if (__all((int)cachedf >= thr)) break;
                        __builtin_amdgcn_s_sleep(4);
                    }
                }
                if (jt > 0 && (int)cachedbp < t - 31) {
                    for (;;) {
                        cachedbp = __hip_atomic_load(bpflag, __ATOMIC_RELAXED,
                                                     __HIP_MEMORY_SCOPE_AGENT);
                        if ((int)cachedbp >= t - 31) break;
                        __builtin_amdgcn_s_sleep(16);
                    }
                }
            }
        }
        __syncthreads();

        // ---- stage h(t): wave wv -> row wv; bypass dwordx4 loads, one wait ----
        {
            const unsigned short* base = hring +
                ((size_t)slot_r * B_DIM + b0 + wv) * H_DIM + kcol0;
            const int cA = lane, cB = lane + 64;
            const bool gA = (cA < CHN), gB = (cB < CHN);
            uint4 o0, o1;
            const unsigned short* a0 = base + cA * 8;
            const unsigned short* a1 = base + cB * 8;
            if (gA) asm volatile("global_load_dwordx4 %0, %1, off sc0 sc1" : "=v"(o0) : "v"(a0));
            if (gB) asm volatile("global_load_dwordx4 %0, %1, off sc0 sc1" : "=v"(o1) : "v"(a1));
            asm volatile("s_waitcnt vmcnt(0)" ::: "memory");
            if (gA) *(uint4*)&ahf[wv * APITCH + cA * 8] = o0;
            if (gB) *(uint4*)&ahf[wv * APITCH + cB * 8] = o1;
        }
        __syncthreads();

        // ---- MFMA: this wave's (jtile, ks slice), 6 gates ----
        f32x4 a0 = 0.f, a1 = 0.f, a2 = 0.f, a3 = 0.f, a4 = 0.f, a5 = 0.f;
        for (int ks = ks_s; ks < ks_e; ++ks) {
            const int off = (ks - jt) * astride;
            const bf16x8 ax = *(const bf16x8*)(pax + off);
            const bf16x8 ah = *(const bf16x8*)(pah + off);
            const unsigned short* pw = pw0 + (size_t)(ks - jt) * 3072;
            const bf16x8 w0 = *(const bf16x8*)(pw);
            const bf16x8 w1 = *(const bf16x8*)(pw + 512);
            const bf16x8 w2 = *(const bf16x8*)(pw + 1024);
            const bf16x8 w3 = *(const bf16x8*)(pw + 1536);
            const bf16x8 w4 = *(const bf16x8*)(pw + 2048);
            const bf16x8 w5 = *(const bf16x8*)(pw + 2560);
            a0 = __builtin_amdgcn_mfma_f32_16x16x32_bf16(ax, w0, a0, 0, 0, 0);
            a1 = __builtin_amdgcn_mfma_f32_16x16x32_bf16(ax, w1, a1, 0, 0, 0);
            a2 = __builtin_amdgcn_mfma_f32_16x16x32_bf16(ax, w2, a2, 0, 0, 0);
            a3 = __builtin_amdgcn_mfma_f32_16x16x32_bf16(ah, w3, a3, 0, 0, 0);
            a4 = __builtin_amdgcn_mfma_f32_16x16x32_bf16(ah, w4, a4, 0, 0, 0);
            a5 = __builtin_amdgcn_mfma_f32_16x16x32_bf16(ah, w5, a5, 0, 0, 0);
        }
        *(f32x4*)&red[wv][0][lane][0] = a0;
        *(f32x4*)&red[wv][1][lane][0] = a1;
        *(f32x4*)&red[wv][2][lane][0] = a2;
        *(f32x4*)&red[wv][3][lane][0] = a3;
        *(f32x4*)&red[wv][4][lane][0] = a4;
        *(f32x4*)&red[wv][5][lane][0] = a5;
        __syncthreads();

        // ---- epilogue: 256 threads = (b 8) x (col 32) ----
        if (tid < 256) {
            const int wb = (ecol >> 4) * 4;
            const int lp = ((eb >> 2) << 4) | (ecol & 15);
            const int rg = eb & 3;
            float s0 = 0, s1 = 0, s2 = 0, s3 = 0, s4 = 0, s5 = 0;
            #pragma unroll
            for (int w2i = 0; w2i < 4; ++w2i) {
                s0 += red[wb + w2i][0][lp][rg]; s1 += red[wb + w2i][1][lp][rg];
                s2 += red[wb + w2i][2][lp][rg]; s3 += red[wb + w2i][3][lp][rg];
                s4 += red[wb + w2i][4][lp][rg]; s5 += red[wb + w2i][5][lp][rg];
            }
            const float xv = x[(size_t)t * B_DIM * H_DIM + (size_t)(b0 + eb) * H_DIM + ej];
            const float hv = hown[eb][ecol];
            const float rp = s0 + c_bir * xv + c_bhr + s3;
            const float zp = s1 + c_biz * xv + c_bhz + s4;
            const float r  = 1.0f / (1.0f + expf(-rp));
            const float z  = 1.0f / (1.0f + expf(-zp));
            const float np = s2 + c_bin * xv + r * (s5 + c_bhn);
            const float n  = tanhf(np);
            const float hnew = hv * z + (1.0f - z) * n;
            hown[eb][ecol] = hnew;
            hb[eb][ecol] = f2bf(hnew);
            float lab = (1.0f / (1.0f + expf(-(hnew * c_wo + bo)))) * xv;
            #pragma unroll
            for (int off = 16; off; off >>= 1)
                lab = fmaxf(lab, __shfl_xor(lab, off));
            if (ecol == 0) pmax[((size_t)t * B_DIM + b0 + eb) * 32 + jt] = lab;
        }
        __syncthreads();

        // ---- publish own 8 rows x 32 cols (bf16) to ring slot t+1 ----
        if (tid < 128) {
            const int b = tid >> 4, cq = tid & 15;
            const unsigned val = (unsigned)hb[b][2 * cq] | ((unsigned)hb[b][2 * cq + 1] << 16);
            unsigned* dst = (unsigned*)(hring +
                ((size_t)slot_w * B_DIM + b0 + b) * H_DIM + 32 * jt) + cq;
            __hip_atomic_store(dst, val, __ATOMIC_RELAXED, __HIP_MEMORY_SCOPE_AGENT);
        }
        __syncthreads();
        if (SYNC) {
            if (tid == 0)
                __hip_atomic_store(myflag, (unsigned)(t + 1),
                                   __ATOMIC_RELEASE, __HIP_MEMORY_SCOPE_AGENT);
        }

        // ---- tail: stage x(t+1) ----
        if (t < T_DIM - 1) {
            const float* src = x + (size_t)(t + 1) * B_DIM * H_DIM
                             + (size_t)(b0 + wv) * H_DIM + kcol0;
            #pragma unroll
            for (int s = 0; s < 2; ++s) {
                const int c8 = lane + (s << 6);
                if (c8 < CHN) {
                    const float4 v0 = *(const float4*)(src + c8 * 8);
                    const float4 v1 = *(const float4*)(src + c8 * 8 + 4);
                    uint4 o = make_uint4(pack2(v0.x, v0.y), pack2(v0.z, v0.w),
                                         pack2(v1.x, v1.y), pack2(v1.z, v1.w));
                    *(uint4*)&axf[wv * APITCH + c8 * 8] = o;
                }
            }
        }
    }
}

// ---------------- finalize: max over 32 block-maxes, threshold, emit int32 ----------------
__global__ __launch_bounds__(256) void finalize(const float* __restrict__ pmax, int* __restrict__ out)
{
    const int i = blockIdx.x * 256 + threadIdx.x; // 0..T*B-1
    if (i >= T_DIM * B_DIM) return;
    const float4* pm = (const float4*)(pmax + (size_t)i * 32);
    float m = -3.4e38f;
    #pragma unroll
    for (int q = 0; q < 8; ++q) {
        const float4 v = pm[q];
        m = fmaxf(m, fmaxf(fmaxf(v.x, v.y), fmaxf(v.z, v.w)));
    }
    out[i] = (m >= 0.5f) ? 1 : -1;
}

extern "C" void kernel_launch(void* const* d_in, const int* in_sizes, int n_in,
                              void* d_out, int out_size, void* d_ws, size_t ws_size,
                              hipStream_t stream)
{
    const float* x    = (const float*)d_in[0];
    const float* h0   = (const float*)d_in[1];
    const float* W_ir = (const float*)d_in[2];
    const float* W_hr = (const float*)d_in[3];
    const float* W_iz = (const float*)d_in[4];
    const float* W_hz = (const float*)d_in[5];
    const float* W_in = (const float*)d_in[6];
    const float* W_hn = (const float*)d_in[7];
    const float* b_ir = (const float*)d_in[8];
    const float* b_hr = (const float*)d_in[9];
    const float* b_iz = (const float*)d_in[10];
    const float* b_hz = (const float*)d_in[11];
    const float* b_in = (const float*)d_in[12];
    const float* b_hn = (const float*)d_in[13];
    const float* W_out = (const float*)d_in[14];
    const float* b_out = (const float*)d_in[15];

    unsigned short* Wpk   = (unsigned short*)d_ws;                    // ~13 MB
    unsigned short* hring = Wpk + (size_t)NBLK * 2 * KSLOT * 3072;    // 8 MB
    float* pmax = (float*)(hring + (size_t)RING * B_DIM * H_DIM);     // 4 MB
    unsigned* prog = (unsigned*)(pmax + (size_t)T_DIM * B_DIM * 32);  // 1 MB

    prep_pack<<<dim3(NBLK * 64, 6), 128, 0, stream>>>(W_ir, W_iz, W_in, W_hr, W_hz, W_hn, Wpk);
    init_h<<<dim3(288), 256, 0, stream>>>(h0, hring, prog);

    void* args[] = {(void*)&x, (void*)&Wpk,
                    (void*)&b_ir, (void*)&b_hr, (void*)&b_iz, (void*)&b_hz,
                    (void*)&b_in, (void*)&b_hn, (void*)&W_out, (void*)&b_out,
                    (void*)&h0, (void*)&hring, (void*)&pmax, (void*)&prog};
    hipError_t rc = hipLaunchCooperativeKernel((const void*)gru_kernel<1>, dim3(256), dim3(512),
                                               args, 0, stream);
    (void)rc;

    finalize<<<dim3(T_DIM * B_DIM / 256), 256, 0, stream>>>(pmax, (int*)d_out);

    // ---- diagnostic probe: identical pipeline, zero inter-WG sync (free-run) ----
    // Runs after finalize; scribbles pmax/hring only (regenerated by next replay's
    // gru_kernel<1>/init_h before any consumer). D_free = dur_us - ~5.7ms.
    gru_kernel<0><<<dim3(256), dim3(512), 0, stream>>>(
        x, Wpk, b_ir, b_hr, b_iz, b_hz, b_in, b_hn, W_out, b_out,
        h0, hring, pmax, prog);
}

// Round 20
// 6156.575 us; speedup vs baseline: 1.3783x; 1.3783x over previous
//
#include <hip/hip_runtime.h>

#define T_DIM 512
#define B_DIM 64
#define H_DIM 1024
#define NBLK 32                // column blocks of 32 cols
#define RING 128               // h-state ring depth (16.8 MB)
#define KSLOT 33               // padded ks capacity: set-decorrelated weight stride
#define APITCH 1032            // x A-frag row pitch in ushorts (2064B)
#define FSTR 1024              // flag stride in u32 (4KB)

typedef __attribute__((ext_vector_type(8))) short bf16x8;
typedef __attribute__((ext_vector_type(4))) float f32x4;

__device__ __forceinline__ unsigned short f2bf(float f) {
    unsigned u = __float_as_uint(f);
    unsigned r = (u + 0x7FFFu + ((u >> 16) & 1u)) >> 16;   // RNE
    return (unsigned short)r;
}
__device__ __forceinline__ unsigned pack2(float a, float b) {
    return (unsigned)f2bf(a) | ((unsigned)f2bf(b) << 16);
}

// ---------------- prep: pack weights into per-(block,jtile) MFMA B-fragment order --------
__global__ __launch_bounds__(128) void prep_pack(
    const float* __restrict__ Wir, const float* __restrict__ Wiz, const float* __restrict__ Win,
    const float* __restrict__ Whr, const float* __restrict__ Whz, const float* __restrict__ Whn,
    unsigned short* __restrict__ Wpk)
{
    const float* srcs[6] = {Wir, Wiz, Win, Whr, Whz, Whn};
    const int bid   = blockIdx.x;            // jt*64 + jtile*32 + ksrel
    const int g     = blockIdx.y;
    const int jt    = bid >> 6;
    const int jtile = (bid >> 5) & 1;
    const int ksrel = bid & 31;
    if (ksrel >= NBLK - jt) return;
    const int t    = threadIdx.x;
    const int lane = t >> 1, e0 = (t & 1) * 4;
    const float* src = srcs[g];
    const int j  = 32 * jt + 16 * jtile + (lane & 15);
    const int kb = (jt + ksrel) * 32 + (lane >> 4) * 8 + e0;
    ushort4 o; unsigned short* po = (unsigned short*)&o;
    #pragma unroll
    for (int i = 0; i < 4; ++i) {
        const int k = kb + i;
        const float w = (k >= j) ? src[(size_t)k * H_DIM + j] : 0.0f;
        po[i] = f2bf(w);
    }
    const size_t idx = ((((size_t)(jt * 2 + jtile) * KSLOT + ksrel) * 6 + g) * 64 + lane) * 8 + e0;
    *(ushort4*)(Wpk + idx) = o;
}

// ---------------- init: h0 -> ring slot 0 (bf16); zero progress flags ----------------
__global__ __launch_bounds__(256) void init_h(const float* __restrict__ h0,
                                              unsigned short* __restrict__ hring,
                                              unsigned* __restrict__ prog)
{
    if (blockIdx.x < 256) {
        const int i = blockIdx.x * 256 + threadIdx.x;   // B*H = 65536
        hring[i] = f2bf(h0[i]);
    } else {
        unsigned* p = prog + (size_t)(blockIdx.x - 256) * 8192 + threadIdx.x;
        #pragma unroll
        for (int k = 0; k < 32; ++k) p[k * 256] = 0u;
    }
}

// ---------------- main: 256 WGs x 512 threads, triangular dataflow ----------------
// Direct ring->register h fragments; register h state; publish from epilogue regs;
// x staged in LDS by waves 4-7 concurrent with epilogue; 3 barriers/step.
__global__ __launch_bounds__(512) void gru_main(
    const float* __restrict__ x,      // [T,B,H]
    const unsigned short* __restrict__ Wpk,
    const float* __restrict__ bir, const float* __restrict__ bhr,
    const float* __restrict__ biz, const float* __restrict__ bhz,
    const float* __restrict__ bin_, const float* __restrict__ bhn,
    const float* __restrict__ Wout, const float* __restrict__ bout,
    const float* __restrict__ h0,
    unsigned short* __restrict__ hring,  // [RING][B][H] bf16
    float* __restrict__ pmax,            // [T,B,32]
    unsigned* __restrict__ prog)         // [8][32] @ FSTR
{
    __shared__ __align__(16) unsigned short axf[8 * APITCH];   // x A-frags (16.5 KB)
    __shared__ __align__(16) unsigned short zblk[8];           // 16B zeros
    __shared__ float red[8][6][64][4];                         // 48 KB

    const int tid  = threadIdx.x;
    const int lane = tid & 63;
    const int wv   = tid >> 6;        // 0..7

    const int jt = blockIdx.x & 31;   // XCD = jt%8 -> weights XCD-pinned
    const int bg = blockIdx.x >> 5;   // 0..7
    const int b0 = bg * 8;

    const int kcol0 = 32 * jt;
    const int CHN   = (H_DIM - kcol0) >> 3;
    const int cnt   = NBLK - jt;
    const int jtile = wv >> 2;
    const int ws4   = wv & 3;
    const int kpw   = (cnt + 3) >> 2;
    const int ks_s  = jt + ws4 * kpw;
    const int ks_e  = (ks_s + kpw < NBLK) ? (ks_s + kpw) : NBLK;
    const int nsl   = (ks_e > ks_s) ? (ks_e - ks_s) : 0;

    const int row = lane & 15;
    const int kg  = lane >> 4;
    const int hrow = (row < 8) ? row : 0;             // clamped (guarded loads only)
    const unsigned short* pax = (row < 8) ? &axf[row * APITCH + kg * 8] : zblk;
    const int astride = (row < 8) ? 32 : 0;
    const unsigned short* pw0 = Wpk + (size_t)(jt * 2 + jtile) * KSLOT * 3072 + lane * 8;

    // epilogue constants (tid<256: eb = tid>>5, ecol = tid&31)
    const int ecol = tid & 31;
    const int eb   = tid >> 5;
    const int ej   = 32 * jt + ecol;
    float c_bir = 0, c_bhr = 0, c_biz = 0, c_bhz = 0, c_bin = 0, c_bhn = 0, c_wo = 0, bo = 0;
    float hreg = 0.0f;                                // own h state, exact f32
    if (tid < 256) {
        c_bir = bir[ej]; c_bhr = bhr[ej]; c_biz = biz[ej]; c_bhz = bhz[ej];
        c_bin = bin_[ej]; c_bhn = bhn[ej]; c_wo = Wout[ej]; bo = bout[0];
        hreg = h0[(size_t)(b0 + eb) * H_DIM + ej];
    }

    unsigned* myflag = prog + (size_t)((bg << 5) + jt) * FSTR;
    unsigned* pollp  = prog + (size_t)((bg << 5) + (lane & 31)) * FSTR;
    unsigned* bpflag = prog + (size_t)(bg << 5) * FSTR;

    if (tid < 8) zblk[tid] = 0;
    // prologue: stage x(0), wave wv -> row wv
    {
        const float* src = x + (size_t)(b0 + wv) * H_DIM + kcol0;
        #pragma unroll
        for (int s = 0; s < 2; ++s) {
            const int c8 = lane + (s << 6);
            if (c8 < CHN) {
                const float4 v0 = *(const float4*)(src + c8 * 8);
                const float4 v1 = *(const float4*)(src + c8 * 8 + 4);
                uint4 o = make_uint4(pack2(v0.x, v0.y), pack2(v0.z, v0.w),
                                     pack2(v1.x, v1.y), pack2(v1.z, v1.w));
                *(uint4*)&axf[wv * APITCH + c8 * 8] = o;
            }
        }
    }

    unsigned cachedf  = 0;
    unsigned cachedbp = 0;

    for (int t = 0; t < T_DIM; ++t) {
        const int slot_r = t & (RING - 1), slot_w = (t + 1) & (RING - 1);

        // ---- poll (wave 0): deps spin-then-sleep; backpressure via single flag ----
        if (wv == 0) {
            const int kt = lane & 31;
            const int thr = (kt > jt) ? t : -0x40000000;
            if (!__all((int)cachedf >= thr)) {
                int spins = 0;
                for (;;) {
                    cachedf = __hip_atomic_load(pollp, __ATOMIC_RELAXED,
                                                __HIP_MEMORY_SCOPE_AGENT);
                    if (__all((int)cachedf >= thr)) break;
                    if (++spins > 24) __builtin_amdgcn_s_sleep(4);
                }
            }
            if (jt > 0 && (int)cachedbp < t - 95) {    // RING=128 overwrite safety
                for (;;) {
                    cachedbp = __hip_atomic_load(bpflag, __ATOMIC_RELAXED,
                                                 __HIP_MEMORY_SCOPE_AGENT);
                    if ((int)cachedbp >= t - 95) break;
                    __builtin_amdgcn_s_sleep(8);
                }
            }
        }
        __syncthreads();   // #1: deps satisfied; axf(t) complete (prev tail)

        // ---- h fragments: ring -> registers, MFMA layout, one vmcnt ----
        uint4 hf[8];
        {
            const unsigned short* hbase = hring +
                ((size_t)slot_r * B_DIM + b0 + hrow) * H_DIM;
            #pragma unroll
            for (int s = 0; s < 8; ++s) {
                hf[s] = make_uint4(0u, 0u, 0u, 0u);
                if (s < nsl && row < 8) {
                    const unsigned short* a = hbase + (ks_s + s) * 32 + kg * 8;
                    asm volatile("global_load_dwordx4 %0, %1, off sc0 sc1"
                                 : "=v"(hf[s]) : "v"(a));
                }
            }
            asm volatile("s_waitcnt vmcnt(0)" ::: "memory");
        }

        // ---- MFMA: this wave's (jtile, ks slice), 6 gates ----
        f32x4 a0 = 0.f, a1 = 0.f, a2 = 0.f, a3 = 0.f, a4 = 0.f, a5 = 0.f;
        #pragma unroll
        for (int s = 0; s < 8; ++s) {
            if (s < nsl) {
                const int ks = ks_s + s;
                const bf16x8 ax = *(const bf16x8*)(pax + (ks - jt) * astride);
                const bf16x8 ah = *(const bf16x8*)&hf[s];
                const unsigned short* pw = pw0 + (size_t)(ks - jt) * 3072;
                const bf16x8 w0 = *(const bf16x8*)(pw);
                const bf16x8 w1 = *(const bf16x8*)(pw + 512);
                const bf16x8 w2 = *(const bf16x8*)(pw + 1024);
                const bf16x8 w3 = *(const bf16x8*)(pw + 1536);
                const bf16x8 w4 = *(const bf16x8*)(pw + 2048);
                const bf16x8 w5 = *(const bf16x8*)(pw + 2560);
                a0 = __builtin_amdgcn_mfma_f32_16x16x32_bf16(ax, w0, a0, 0, 0, 0);
                a1 = __builtin_amdgcn_mfma_f32_16x16x32_bf16(ax, w1, a1, 0, 0, 0);
                a2 = __builtin_amdgcn_mfma_f32_16x16x32_bf16(ax, w2, a2, 0, 0, 0);
                a3 = __builtin_amdgcn_mfma_f32_16x16x32_bf16(ah, w3, a3, 0, 0, 0);
                a4 = __builtin_amdgcn_mfma_f32_16x16x32_bf16(ah, w4, a4, 0, 0, 0);
                a5 = __builtin_amdgcn_mfma_f32_16x16x32_bf16(ah, w5, a5, 0, 0, 0);
            }
        }
        *(f32x4*)&red[wv][0][lane][0] = a0;
        *(f32x4*)&red[wv][1][lane][0] = a1;
        *(f32x4*)&red[wv][2][lane][0] = a2;
        *(f32x4*)&red[wv][3][lane][0] = a3;
        *(f32x4*)&red[wv][4][lane][0] = a4;
        *(f32x4*)&red[wv][5][lane][0] = a5;
        __syncthreads();   // #2: red complete

        // ---- epilogue (waves 0-3)  ||  x(t+1) stage (waves 4-7) ----
        if (tid < 256) {
            const int wb = (ecol >> 4) * 4;
            const int lp = ((eb >> 2) << 4) | (ecol & 15);
            const int rg = eb & 3;
            float s0 = 0, s1 = 0, s2 = 0, s3 = 0, s4 = 0, s5 = 0;
            #pragma unroll
            for (int w2i = 0; w2i < 4; ++w2i) {
                s0 += red[wb + w2i][0][lp][rg]; s1 += red[wb + w2i][1][lp][rg];
                s2 += red[wb + w2i][2][lp][rg]; s3 += red[wb + w2i][3][lp][rg];
                s4 += red[wb + w2i][4][lp][rg]; s5 += red[wb + w2i][5][lp][rg];
            }
            const float xv = x[(size_t)t * B_DIM * H_DIM + (size_t)(b0 + eb) * H_DIM + ej];
            const float rp = s0 + c_bir * xv + c_bhr + s3;
            const float zp = s1 + c_biz * xv + c_bhz + s4;
            const float r  = 1.0f / (1.0f + expf(-rp));
            const float z  = 1.0f / (1.0f + expf(-zp));
            const float np = s2 + c_bin * xv + r * (s5 + c_bhn);
            const float n  = tanhf(np);
            const float hnew = hreg * z + (1.0f - z) * n;
            hreg = hnew;
            // publish: pack bf16 pair via shfl, even-col threads store u32
            const unsigned mybf = (unsigned)f2bf(hnew);
            const unsigned other = (unsigned)__shfl_xor((int)mybf, 1);
            if ((ecol & 1) == 0) {
                const unsigned val = mybf | (other << 16);
                unsigned* dst = (unsigned*)(hring +
                    ((size_t)slot_w * B_DIM + b0 + eb) * H_DIM + 32 * jt + ecol);
                __hip_atomic_store(dst, val, __ATOMIC_RELAXED, __HIP_MEMORY_SCOPE_AGENT);
            }
            float lab = (1.0f / (1.0f + expf(-(hnew * c_wo + bo)))) * xv;
            #pragma unroll
            for (int off = 16; off; off >>= 1)
                lab = fmaxf(lab, __shfl_xor(lab, off));
            if (ecol == 0) pmax[((size_t)t * B_DIM + b0 + eb) * 32 + jt] = lab;
        } else if (t < T_DIM - 1) {
            // waves 4-7: stage x(t+1), 2 rows each
            const float* xs = x + (size_t)(t + 1) * B_DIM * H_DIM;
            #pragma unroll
            for (int rr = 0; rr < 2; ++rr) {
                const int r = 2 * (wv - 4) + rr;
                const float* src = xs + (size_t)(b0 + r) * H_DIM + kcol0;
                #pragma unroll
                for (int s = 0; s < 2; ++s) {
                    const int c8 = lane + (s << 6);
                    if (c8 < CHN) {
                        const float4 v0 = *(const float4*)(src + c8 * 8);
                        const float4 v1 = *(const float4*)(src + c8 * 8 + 4);
                        uint4 o = make_uint4(pack2(v0.x, v0.y), pack2(v0.z, v0.w),
                                             pack2(v1.x, v1.y), pack2(v1.z, v1.w));
                        *(uint4*)&axf[r * APITCH + c8 * 8] = o;
                    }
                }
            }
        }
        __syncthreads();   // #3: publish stores drained (vmcnt0), axf(t+1) complete

        if (tid == 0)
            __hip_atomic_store(myflag, (unsigned)(t + 1),
                               __ATOMIC_RELEASE, __HIP_MEMORY_SCOPE_AGENT);
    }
}

// ---------------- finalize: max over 32 block-maxes, threshold, emit int32 ----------------
__global__ __launch_bounds__(256) void finalize(const float* __restrict__ pmax, int* __restrict__ out)
{
    const int i = blockIdx.x * 256 + threadIdx.x; // 0..T*B-1
    if (i >= T_DIM * B_DIM) return;
    const float4* pm = (const float4*)(pmax + (size_t)i * 32);
    float m = -3.4e38f;
    #pragma unroll
    for (int q = 0; q < 8; ++q) {
        const float4 v = pm[q];
        m = fmaxf(m, fmaxf(fmaxf(v.x, v.y), fmaxf(v.z, v.w)));
    }
    out[i] = (m >= 0.5f) ? 1 : -1;
}

extern "C" void kernel_launch(void* const* d_in, const int* in_sizes, int n_in,
                              void* d_out, int out_size, void* d_ws, size_t ws_size,
                              hipStream_t stream)
{
    const float* x    = (const float*)d_in[0];
    const float* h0   = (const float*)d_in[1];
    const float* W_ir = (const float*)d_in[2];
    const float* W_hr = (const float*)d_in[3];
    const float* W_iz = (const float*)d_in[4];
    const float* W_hz = (const float*)d_in[5];
    const float* W_in = (const float*)d_in[6];
    const float* W_hn = (const float*)d_in[7];
    const float* b_ir = (const float*)d_in[8];
    const float* b_hr = (const float*)d_in[9];
    const float* b_iz = (const float*)d_in[10];
    const float* b_hz = (const float*)d_in[11];
    const float* b_in = (const float*)d_in[12];
    const float* b_hn = (const float*)d_in[13];
    const float* W_out = (const float*)d_in[14];
    const float* b_out = (const float*)d_in[15];

    unsigned short* Wpk   = (unsigned short*)d_ws;                    // ~13 MB
    unsigned short* hring = Wpk + (size_t)NBLK * 2 * KSLOT * 3072;    // 16.8 MB
    float* pmax = (float*)(hring + (size_t)RING * B_DIM * H_DIM);     // 4 MB
    unsigned* prog = (unsigned*)(pmax + (size_t)T_DIM * B_DIM * 32);  // 1 MB

    prep_pack<<<dim3(NBLK * 64, 6), 128, 0, stream>>>(W_ir, W_iz, W_in, W_hr, W_hz, W_hn, Wpk);
    init_h<<<dim3(288), 256, 0, stream>>>(h0, hring, prog);

    void* args[] = {(void*)&x, (void*)&Wpk,
                    (void*)&b_ir, (void*)&b_hr, (void*)&b_iz, (void*)&b_hz,
                    (void*)&b_in, (void*)&b_hn, (void*)&W_out, (void*)&b_out,
                    (void*)&h0, (void*)&hring, (void*)&pmax, (void*)&prog};
    hipError_t rc = hipLaunchCooperativeKernel((const void*)gru_main, dim3(256), dim3(512),
                                               args, 0, stream);
    (void)rc;

    finalize<<<dim3(T_DIM * B_DIM / 256), 256, 0, stream>>>(pmax, (int*)d_out);
}

// Round 21
// 6036.815 us; speedup vs baseline: 1.4057x; 1.0198x over previous
//
#include <hip/hip_runtime.h>

#define T_DIM 512
#define B_DIM 64
#define H_DIM 1024
#define NBLK 32                // column blocks of 32 cols
#define RING 64                // h-state ring depth
#define KSLOT 33               // padded ks capacity: set-decorrelated weight stride
#define APITCH 1032            // A-frag row pitch in ushorts (2064B)
#define FSTR 1024              // flag stride in u32 (4KB)

typedef __attribute__((ext_vector_type(8))) short bf16x8;
typedef __attribute__((ext_vector_type(4))) float f32x4;

__device__ __forceinline__ unsigned short f2bf(float f) {
    unsigned u = __float_as_uint(f);
    unsigned r = (u + 0x7FFFu + ((u >> 16) & 1u)) >> 16;   // RNE
    return (unsigned short)r;
}
__device__ __forceinline__ unsigned pack2(float a, float b) {
    return (unsigned)f2bf(a) | ((unsigned)f2bf(b) << 16);
}

// ---------------- prep: pack weights into per-(block,jtile) MFMA B-fragment order --------
__global__ __launch_bounds__(128) void prep_pack(
    const float* __restrict__ Wir, const float* __restrict__ Wiz, const float* __restrict__ Win,
    const float* __restrict__ Whr, const float* __restrict__ Whz, const float* __restrict__ Whn,
    unsigned short* __restrict__ Wpk)
{
    const float* srcs[6] = {Wir, Wiz, Win, Whr, Whz, Whn};
    const int bid   = blockIdx.x;            // jt*64 + jtile*32 + ksrel
    const int g     = blockIdx.y;
    const int jt    = bid >> 6;
    const int jtile = (bid >> 5) & 1;
    const int ksrel = bid & 31;
    if (ksrel >= NBLK - jt) return;
    const int t    = threadIdx.x;
    const int lane = t >> 1, e0 = (t & 1) * 4;
    const float* src = srcs[g];
    const int j  = 32 * jt + 16 * jtile + (lane & 15);
    const int kb = (jt + ksrel) * 32 + (lane >> 4) * 8 + e0;
    ushort4 o; unsigned short* po = (unsigned short*)&o;
    #pragma unroll
    for (int i = 0; i < 4; ++i) {
        const int k = kb + i;
        const float w = (k >= j) ? src[(size_t)k * H_DIM + j] : 0.0f;
        po[i] = f2bf(w);
    }
    const size_t idx = ((((size_t)(jt * 2 + jtile) * KSLOT + ksrel) * 6 + g) * 64 + lane) * 8 + e0;
    *(ushort4*)(Wpk + idx) = o;
}

// ---------------- init: h0 -> ring slot 0 (bf16); zero progress flags ----------------
__global__ __launch_bounds__(256) void init_h(const float* __restrict__ h0,
                                              unsigned short* __restrict__ hring,
                                              unsigned* __restrict__ prog)
{
    if (blockIdx.x < 256) {
        const int i = blockIdx.x * 256 + threadIdx.x;   // B*H = 65536
        hring[i] = f2bf(h0[i]);
    } else {
        unsigned* p = prog + (size_t)(blockIdx.x - 256) * 8192 + threadIdx.x;
        #pragma unroll
        for (int k = 0; k < 32; ++k) p[k * 256] = 0u;
    }
}

// ---------------- main: 256 WGs x 512 threads, far/near split triangular dataflow ------
// Far slices (ks >= jt+2: blocks >=2 edges ahead) computed first; the binding
// near-neighbor (jt+1) is polled only after far compute -> its publish latency
// hides under ~3us of far MFMA. Publish from epilogue regs; flag before label/pmax.
__global__ __launch_bounds__(512) void gru_main(
    const float* __restrict__ x,      // [T,B,H]
    const unsigned short* __restrict__ Wpk,
    const float* __restrict__ bir, const float* __restrict__ bhr,
    const float* __restrict__ biz, const float* __restrict__ bhz,
    const float* __restrict__ bin_, const float* __restrict__ bhn,
    const float* __restrict__ Wout, const float* __restrict__ bout,
    const float* __restrict__ h0,
    unsigned short* __restrict__ hring,  // [RING][B][H] bf16
    float* __restrict__ pmax,            // [T,B,32]
    unsigned* __restrict__ prog)         // [8][32] @ FSTR
{
    __shared__ __align__(16) unsigned short axf[8 * APITCH];   // x A-frags (16.5 KB)
    __shared__ __align__(16) unsigned short ahf[8 * APITCH];   // h A-frags (16.5 KB)
    __shared__ __align__(16) unsigned short zblk[8];           // 16B zeros
    __shared__ float red[8][6][64][4];                         // 48 KB

    const int tid  = threadIdx.x;
    const int lane = tid & 63;
    const int wv   = tid >> 6;        // 0..7

    const int jt = blockIdx.x & 31;   // XCD = jt%8 -> weights XCD-pinned
    const int bg = blockIdx.x >> 5;   // 0..7
    const int b0 = bg * 8;

    const int kcol0 = 32 * jt;
    const int CHN   = (H_DIM - kcol0) >> 3;   // chunks (16B) per staged row
    const int cnt   = NBLK - jt;
    const int jtile = wv >> 2;
    const int ws4   = wv & 3;
    const int kpw   = (cnt + 3) >> 2;
    const int ks_s  = jt + ws4 * kpw;
    const int ks_e  = (ks_s + kpw < NBLK) ? (ks_s + kpw) : NBLK;

    const int kb     = (jt + 2 < NBLK) ? (jt + 2) : NBLK;   // near/far boundary
    const int nearch = 4 * (kb - jt);                       // near chunks (<= 8)
    const int fs     = (ks_s > kb) ? ks_s : kb;             // far slice start
    const int ne     = (ks_e < kb) ? ks_e : kb;             // near slice end

    const int row = lane & 15;
    const int kg  = lane >> 4;
    const unsigned short* pax = (row < 8) ? &axf[row * APITCH + kg * 8] : zblk;
    const unsigned short* pah = (row < 8) ? &ahf[row * APITCH + kg * 8] : zblk;
    const int astride = (row < 8) ? 32 : 0;
    const unsigned short* pw0 = Wpk + (size_t)(jt * 2 + jtile) * KSLOT * 3072 + lane * 8;

    // epilogue constants (tid<256: eb = tid>>5, ecol = tid&31)
    const int ecol = tid & 31;
    const int eb   = tid >> 5;
    const int ej   = 32 * jt + ecol;
    float c_bir = 0, c_bhr = 0, c_biz = 0, c_bhz = 0, c_bin = 0, c_bhn = 0, c_wo = 0, bo = 0;
    float hreg = 0.0f;
    if (tid < 256) {
        c_bir = bir[ej]; c_bhr = bhr[ej]; c_biz = biz[ej]; c_bhz = bhz[ej];
        c_bin = bin_[ej]; c_bhn = bhn[ej]; c_wo = Wout[ej]; bo = bout[0];
        hreg = h0[(size_t)(b0 + eb) * H_DIM + ej];
    }

    unsigned* myflag = prog + (size_t)((bg << 5) + jt) * FSTR;
    unsigned* pollp  = prog + (size_t)((bg << 5) + (lane & 31)) * FSTR;
    unsigned* bpflag = prog + (size_t)(bg << 5) * FSTR;

    if (tid < 8) zblk[tid] = 0;
    // prologue: stage x(0), wave wv -> row wv
    {
        const float* src = x + (size_t)(b0 + wv) * H_DIM + kcol0;
        #pragma unroll
        for (int s = 0; s < 2; ++s) {
            const int c8 = lane + (s << 6);
            if (c8 < CHN) {
                const float4 v0 = *(const float4*)(src + c8 * 8);
                const float4 v1 = *(const float4*)(src + c8 * 8 + 4);
                uint4 o = make_uint4(pack2(v0.x, v0.y), pack2(v0.z, v0.w),
                                     pack2(v1.x, v1.y), pack2(v1.z, v1.w));
                *(uint4*)&axf[wv * APITCH + c8 * 8] = o;
            }
        }
    }

    unsigned cachedf  = 0;    // wave 0: cached flags (monotone -> safe)
    unsigned cachedbp = 0;

    for (int t = 0; t < T_DIM; ++t) {
        const int slot_r = t & (RING - 1), slot_w = (t + 1) & (RING - 1);

        // ---- far poll (wave 0): kt >= kb at t; backpressure via prog(0) ----
        if (wv == 0) {
            const int kt = lane & 31;
            const int thrF = (kt >= kb) ? t : -0x40000000;
            if (!__all((int)cachedf >= thrF)) {
                int spins = 0;
                for (;;) {
                    cachedf = __hip_atomic_load(pollp, __ATOMIC_RELAXED,
                                                __HIP_MEMORY_SCOPE_AGENT);
                    if (__all((int)cachedf >= thrF)) break;
                    if (++spins > 24) __builtin_amdgcn_s_sleep(4);
                }
            }
            if (jt > 0 && (int)cachedbp < t - 31) {
                for (;;) {
                    cachedbp = __hip_atomic_load(bpflag, __ATOMIC_RELAXED,
                                                 __HIP_MEMORY_SCOPE_AGENT);
                    if ((int)cachedbp >= t - 31) break;
                    __builtin_amdgcn_s_sleep(16);
                }
            }
        }
        __syncthreads();   // #1: far deps ok; axf(t) complete

        // ---- far h stage: row wv, chunks [nearch, CHN), bypass dwordx4 ----
        {
            const unsigned short* base = hring +
                ((size_t)slot_r * B_DIM + b0 + wv) * H_DIM + kcol0;
            const int cA = lane, cB = lane + 64;
            const bool gA = (cA >= nearch && cA < CHN), gB = (cB >= nearch && cB < CHN);
            uint4 o0, o1;
            const unsigned short* a0 = base + cA * 8;
            const unsigned short* a1 = base + cB * 8;
            if (gA) asm volatile("global_load_dwordx4 %0, %1, off sc0 sc1" : "=v"(o0) : "v"(a0));
            if (gB) asm volatile("global_load_dwordx4 %0, %1, off sc0 sc1" : "=v"(o1) : "v"(a1));
            asm volatile("s_waitcnt vmcnt(0)" ::: "memory");
            if (gA) *(uint4*)&ahf[wv * APITCH + cA * 8] = o0;
            if (gB) *(uint4*)&ahf[wv * APITCH + cB * 8] = o1;
        }
        __syncthreads();   // #2: far h staged

        // ---- far MFMA: ks in [fs, ks_e) ----
        f32x4 a0 = 0.f, a1 = 0.f, a2 = 0.f, a3 = 0.f, a4 = 0.f, a5 = 0.f;
        for (int ks = fs; ks < ks_e; ++ks) {
            const int off = (ks - jt) * astride;
            const bf16x8 ax = *(const bf16x8*)(pax + off);
            const bf16x8 ah = *(const bf16x8*)(pah + off);
            const unsigned short* pw = pw0 + (size_t)(ks - jt) * 3072;
            const bf16x8 w0 = *(const bf16x8*)(pw);
            const bf16x8 w1 = *(const bf16x8*)(pw + 512);
            const bf16x8 w2 = *(const bf16x8*)(pw + 1024);
            const bf16x8 w3 = *(const bf16x8*)(pw + 1536);
            const bf16x8 w4 = *(const bf16x8*)(pw + 2048);
            const bf16x8 w5 = *(const bf16x8*)(pw + 2560);
            a0 = __builtin_amdgcn_mfma_f32_16x16x32_bf16(ax, w0, a0, 0, 0, 0);
            a1 = __builtin_amdgcn_mfma_f32_16x16x32_bf16(ax, w1, a1, 0, 0, 0);
            a2 = __builtin_amdgcn_mfma_f32_16x16x32_bf16(ax, w2, a2, 0, 0, 0);
            a3 = __builtin_amdgcn_mfma_f32_16x16x32_bf16(ah, w3, a3, 0, 0, 0);
            a4 = __builtin_amdgcn_mfma_f32_16x16x32_bf16(ah, w4, a4, 0, 0, 0);
            a5 = __builtin_amdgcn_mfma_f32_16x16x32_bf16(ah, w5, a5, 0, 0, 0);
        }

        // ---- near poll (wave 0): jt < kt < kb at t -- fires AFTER far compute ----
        if (wv == 0) {
            const int kt = lane & 31;
            const int thrN = (kt > jt && kt < kb) ? t : -0x40000000;
            if (!__all((int)cachedf >= thrN)) {
                int spins = 0;
                for (;;) {
                    cachedf = __hip_atomic_load(pollp, __ATOMIC_RELAXED,
                                                __HIP_MEMORY_SCOPE_AGENT);
                    if (__all((int)cachedf >= thrN)) break;
                    if (++spins > 64) __builtin_amdgcn_s_sleep(2);
                }
            }
        }
        __syncthreads();   // #3: near deps ok

        // ---- near h stage: row wv, chunks [0, nearch) ----
        {
            const unsigned short* base = hring +
                ((size_t)slot_r * B_DIM + b0 + wv) * H_DIM + kcol0;
            uint4 o0;
            const bool gA = (lane < nearch);
            const unsigned short* a0p = base + lane * 8;
            if (gA) asm volatile("global_load_dwordx4 %0, %1, off sc0 sc1" : "=v"(o0) : "v"(a0p));
            asm volatile("s_waitcnt vmcnt(0)" ::: "memory");
            if (gA) *(uint4*)&ahf[wv * APITCH + lane * 8] = o0;
        }
        __syncthreads();   // #4: near h staged

        // ---- near MFMA: ks in [ks_s, ne) ----
        for (int ks = ks_s; ks < ne; ++ks) {
            const int off = (ks - jt) * astride;
            const bf16x8 ax = *(const bf16x8*)(pax + off);
            const bf16x8 ah = *(const bf16x8*)(pah + off);
            const unsigned short* pw = pw0 + (size_t)(ks - jt) * 3072;
            const bf16x8 w0 = *(const bf16x8*)(pw);
            const bf16x8 w1 = *(const bf16x8*)(pw + 512);
            const bf16x8 w2 = *(const bf16x8*)(pw + 1024);
            const bf16x8 w3 = *(const bf16x8*)(pw + 1536);
            const bf16x8 w4 = *(const bf16x8*)(pw + 2048);
            const bf16x8 w5 = *(const bf16x8*)(pw + 2560);
            a0 = __builtin_amdgcn_mfma_f32_16x16x32_bf16(ax, w0, a0, 0, 0, 0);
            a1 = __builtin_amdgcn_mfma_f32_16x16x32_bf16(ax, w1, a1, 0, 0, 0);
            a2 = __builtin_amdgcn_mfma_f32_16x16x32_bf16(ax, w2, a2, 0, 0, 0);
            a3 = __builtin_amdgcn_mfma_f32_16x16x32_bf16(ah, w3, a3, 0, 0, 0);
            a4 = __builtin_amdgcn_mfma_f32_16x16x32_bf16(ah, w4, a4, 0, 0, 0);
            a5 = __builtin_amdgcn_mfma_f32_16x16x32_bf16(ah, w5, a5, 0, 0, 0);
        }
        *(f32x4*)&red[wv][0][lane][0] = a0;
        *(f32x4*)&red[wv][1][lane][0] = a1;
        *(f32x4*)&red[wv][2][lane][0] = a2;
        *(f32x4*)&red[wv][3][lane][0] = a3;
        *(f32x4*)&red[wv][4][lane][0] = a4;
        *(f32x4*)&red[wv][5][lane][0] = a5;
        __syncthreads();   // #5: red complete (axf free)

        // ---- epilogue + publish (waves 0-3)  ||  x(t+1) stage (waves 4-7) ----
        float xv = 0.0f;
        if (tid < 256) {
            const int wb = (ecol >> 4) * 4;
            const int lp = ((eb >> 2) << 4) | (ecol & 15);
            const int rg = eb & 3;
            float s0 = 0, s1 = 0, s2 = 0, s3 = 0, s4 = 0, s5 = 0;
            #pragma unroll
            for (int w2i = 0; w2i < 4; ++w2i) {
                s0 += red[wb + w2i][0][lp][rg]; s1 += red[wb + w2i][1][lp][rg];
                s2 += red[wb + w2i][2][lp][rg]; s3 += red[wb + w2i][3][lp][rg];
                s4 += red[wb + w2i][4][lp][rg]; s5 += red[wb + w2i][5][lp][rg];
            }
            xv = x[(size_t)t * B_DIM * H_DIM + (size_t)(b0 + eb) * H_DIM + ej];
            const float rp = s0 + c_bir * xv + c_bhr + s3;
            const float zp = s1 + c_biz * xv + c_bhz + s4;
            const float r  = 1.0f / (1.0f + expf(-rp));
            const float z  = 1.0f / (1.0f + expf(-zp));
            const float np = s2 + c_bin * xv + r * (s5 + c_bhn);
            const float n  = tanhf(np);
            const float hnew = hreg * z + (1.0f - z) * n;
            hreg = hnew;
            // publish immediately: pack bf16 pair via shfl, even-col lanes store u32
            const unsigned mybf = (unsigned)f2bf(hnew);
            const unsigned other = (unsigned)__shfl_xor((int)mybf, 1);
            if ((ecol & 1) == 0) {
                const unsigned val = mybf | (other << 16);
                unsigned* dst = (unsigned*)(hring +
                    ((size_t)slot_w * B_DIM + b0 + eb) * H_DIM + 32 * jt + ecol);
                __hip_atomic_store(dst, val, __ATOMIC_RELAXED, __HIP_MEMORY_SCOPE_AGENT);
            }
        } else if (t < T_DIM - 1) {
            const float* xs = x + (size_t)(t + 1) * B_DIM * H_DIM;
            #pragma unroll
            for (int rr = 0; rr < 2; ++rr) {
                const int r = 2 * (wv - 4) + rr;
                const float* src = xs + (size_t)(b0 + r) * H_DIM + kcol0;
                #pragma unroll
                for (int s = 0; s < 2; ++s) {
                    const int c8 = lane + (s << 6);
                    if (c8 < CHN) {
                        const float4 v0 = *(const float4*)(src + c8 * 8);
                        const float4 v1 = *(const float4*)(src + c8 * 8 + 4);
                        uint4 o = make_uint4(pack2(v0.x, v0.y), pack2(v0.z, v0.w),
                                             pack2(v1.x, v1.y), pack2(v1.z, v1.w));
                        *(uint4*)&axf[r * APITCH + c8 * 8] = o;
                    }
                }
            }
        }
        __syncthreads();   // #6: publish stores drained; axf(t+1) complete

        if (tid == 0)
            __hip_atomic_store(myflag, (unsigned)(t + 1),
                               __ATOMIC_RELEASE, __HIP_MEMORY_SCOPE_AGENT);

        // ---- post-flag: label + pmax (off the critical sync path) ----
        if (tid < 256) {
            float lab = (1.0f / (1.0f + expf(-(hreg * c_wo + bo)))) * xv;
            #pragma unroll
            for (int off = 16; off; off >>= 1)
                lab = fmaxf(lab, __shfl_xor(lab, off));
            if (ecol == 0) pmax[((size_t)t * B_DIM + b0 + eb) * 32 + jt] = lab;
        }
    }
}

// ---------------- finalize: max over 32 block-maxes, threshold, emit int32 ----------------
__global__ __launch_bounds__(256) void finalize(const float* __restrict__ pmax, int* __restrict__ out)
{
    const int i = blockIdx.x * 256 + threadIdx.x; // 0..T*B-1
    if (i >= T_DIM * B_DIM) return;
    const float4* pm = (const float4*)(pmax + (size_t)i * 32);
    float m = -3.4e38f;
    #pragma unroll
    for (int q = 0; q < 8; ++q) {
        const float4 v = pm[q];
        m = fmaxf(m, fmaxf(fmaxf(v.x, v.y), fmaxf(v.z, v.w)));
    }
    out[i] = (m >= 0.5f) ? 1 : -1;
}

extern "C" void kernel_launch(void* const* d_in, const int* in_sizes, int n_in,
                              void* d_out, int out_size, void* d_ws, size_t ws_size,
                              hipStream_t stream)
{
    const float* x    = (const float*)d_in[0];
    const float* h0   = (const float*)d_in[1];
    const float* W_ir = (const float*)d_in[2];
    const float* W_hr = (const float*)d_in[3];
    const float* W_iz = (const float*)d_in[4];
    const float* W_hz = (const float*)d_in[5];
    const float* W_in = (const float*)d_in[6];
    const float* W_hn = (const float*)d_in[7];
    const float* b_ir = (const float*)d_in[8];
    const float* b_hr = (const float*)d_in[9];
    const float* b_iz = (const float*)d_in[10];
    const float* b_hz = (const float*)d_in[11];
    const float* b_in = (const float*)d_in[12];
    const float* b_hn = (const float*)d_in[13];
    const float* W_out = (const float*)d_in[14];
    const float* b_out = (const float*)d_in[15];

    unsigned short* Wpk   = (unsigned short*)d_ws;                    // ~13 MB
    unsigned short* hring = Wpk + (size_t)NBLK * 2 * KSLOT * 3072;    // 8 MB
    float* pmax = (float*)(hring + (size_t)RING * B_DIM * H_DIM);     // 4 MB
    unsigned* prog = (unsigned*)(pmax + (size_t)T_DIM * B_DIM * 32);  // 1 MB

    prep_pack<<<dim3(NBLK * 64, 6), 128, 0, stream>>>(W_ir, W_iz, W_in, W_hr, W_hz, W_hn, Wpk);
    init_h<<<dim3(288), 256, 0, stream>>>(h0, hring, prog);

    void* args[] = {(void*)&x, (void*)&Wpk,
                    (void*)&b_ir, (void*)&b_hr, (void*)&b_iz, (void*)&b_hz,
                    (void*)&b_in, (void*)&b_hn, (void*)&W_out, (void*)&b_out,
                    (void*)&h0, (void*)&hring, (void*)&pmax, (void*)&prog};
    hipError_t rc = hipLaunchCooperativeKernel((const void*)gru_main, dim3(256), dim3(512),
                                               args, 0, stream);
    (void)rc;

    finalize<<<dim3(T_DIM * B_DIM / 256), 256, 0, stream>>>(pmax, (int*)d_out);
}

// Round 22
// 5647.552 us; speedup vs baseline: 1.5026x; 1.0689x over previous
//
#include <hip/hip_runtime.h>

#define T_DIM 512
#define B_DIM 64
#define H_DIM 1024
#define NBLK 32                // column blocks of 32 cols
#define RING 64                // h-state ring depth
#define AHEAD 62               // max run-ahead (ring-overwrite-safe)
#define KSLOT 33               // padded ks capacity: set-decorrelated weight stride
#define APITCH 1032            // A-frag row pitch in ushorts (2064B)
#define FSTR 1024              // flag stride in u32 (4KB)

typedef __attribute__((ext_vector_type(8))) short bf16x8;
typedef __attribute__((ext_vector_type(4))) float f32x4;

// ws layout:
//   Wpk   [32 jt][2 jtile][33 ksrel][6 g][64 lane][8 e] bf16  B-fragments, tril-masked
//   hring [64][B][H] bf16                                     h state ring (agent-coherent)
//   pmax  [T][B][32] f32                                      per-block label maxes
//   prog  [8 bg][32 jt] u32 @ 4KB stride (1 MB)               progress flags
//         block-0 lines carry 4 replicas at +16*r u32 (64B apart) for bp waiters

__device__ __forceinline__ unsigned short f2bf(float f) {
    unsigned u = __float_as_uint(f);
    unsigned r = (u + 0x7FFFu + ((u >> 16) & 1u)) >> 16;   // RNE
    return (unsigned short)r;
}
__device__ __forceinline__ unsigned pack2(float a, float b) {
    return (unsigned)f2bf(a) | ((unsigned)f2bf(b) << 16);
}

// ---------------- prep: pack weights into per-(block,jtile) MFMA B-fragment order --------
__global__ __launch_bounds__(128) void prep_pack(
    const float* __restrict__ Wir, const float* __restrict__ Wiz, const float* __restrict__ Win,
    const float* __restrict__ Whr, const float* __restrict__ Whz, const float* __restrict__ Whn,
    unsigned short* __restrict__ Wpk)
{
    const float* srcs[6] = {Wir, Wiz, Win, Whr, Whz, Whn};
    const int bid   = blockIdx.x;            // jt*64 + jtile*32 + ksrel
    const int g     = blockIdx.y;
    const int jt    = bid >> 6;
    const int jtile = (bid >> 5) & 1;
    const int ksrel = bid & 31;
    if (ksrel >= NBLK - jt) return;
    const int t    = threadIdx.x;
    const int lane = t >> 1, e0 = (t & 1) * 4;
    const float* src = srcs[g];
    const int j  = 32 * jt + 16 * jtile + (lane & 15);
    const int kb = (jt + ksrel) * 32 + (lane >> 4) * 8 + e0;
    ushort4 o; unsigned short* po = (unsigned short*)&o;
    #pragma unroll
    for (int i = 0; i < 4; ++i) {
        const int k = kb + i;
        const float w = (k >= j) ? src[(size_t)k * H_DIM + j] : 0.0f;
        po[i] = f2bf(w);
    }
    const size_t idx = ((((size_t)(jt * 2 + jtile) * KSLOT + ksrel) * 6 + g) * 64 + lane) * 8 + e0;
    *(ushort4*)(Wpk + idx) = o;
}

// ---------------- init: h0 -> ring slot 0 (bf16); zero progress flags ----------------
__global__ __launch_bounds__(256) void init_h(const float* __restrict__ h0,
                                              unsigned short* __restrict__ hring,
                                              unsigned* __restrict__ prog)
{
    if (blockIdx.x < 256) {
        const int i = blockIdx.x * 256 + threadIdx.x;   // B*H = 65536
        hring[i] = f2bf(h0[i]);
    } else {
        unsigned* p = prog + (size_t)(blockIdx.x - 256) * 8192 + threadIdx.x;
        #pragma unroll
        for (int k = 0; k < 32; ++k) p[k * 256] = 0u;
    }
}

// ---------------- main: 256 WGs x 512 threads, triangular dataflow, replicated bp flag --
__global__ __launch_bounds__(512) void gru_main(
    const float* __restrict__ x,      // [T,B,H]
    const unsigned short* __restrict__ Wpk,
    const float* __restrict__ bir, const float* __restrict__ bhr,
    const float* __restrict__ biz, const float* __restrict__ bhz,
    const float* __restrict__ bin_, const float* __restrict__ bhn,
    const float* __restrict__ Wout, const float* __restrict__ bout,
    const float* __restrict__ h0,
    unsigned short* __restrict__ hring,  // [RING][B][H] bf16
    float* __restrict__ pmax,            // [T,B,32]
    unsigned* __restrict__ prog)         // [8][32] @ FSTR
{
    __shared__ __align__(16) unsigned short axf[8 * APITCH];   // x A-frags (16.5 KB)
    __shared__ __align__(16) unsigned short ahf[8 * APITCH];   // h A-frags (16.5 KB)
    __shared__ __align__(16) unsigned short zblk[8];           // 16B zeros
    __shared__ float red[8][6][64][4];                         // 48 KB
    __shared__ float hown[8][33];                              // own-block h, f32 exact
    __shared__ unsigned short hb[8][32];                       // own-block h, bf16

    const int tid  = threadIdx.x;
    const int lane = tid & 63;
    const int wv   = tid >> 6;        // 0..7

    const int jt = blockIdx.x & 31;   // XCD = jt%8
    const int bg = blockIdx.x >> 5;   // 0..7
    const int b0 = bg * 8;

    const int kcol0 = 32 * jt;
    const int CHN   = (H_DIM - kcol0) >> 3;
    const int cnt   = NBLK - jt;
    const int jtile = wv >> 2;
    const int ws4   = wv & 3;
    const int kpw   = (cnt + 3) >> 2;
    const int ks_s  = jt + ws4 * kpw;
    const int ks_e  = (ks_s + kpw < NBLK) ? (ks_s + kpw) : NBLK;

    const int row = lane & 15;
    const int kg  = lane >> 4;
    const unsigned short* pax = (row < 8) ? &axf[row * APITCH + kg * 8] : zblk;
    const unsigned short* pah = (row < 8) ? &ahf[row * APITCH + kg * 8] : zblk;
    const int astride = (row < 8) ? 32 : 0;
    const unsigned short* pw0 = Wpk + (size_t)(jt * 2 + jtile) * KSLOT * 3072 + lane * 8;

    // epilogue constants (tid<256: eb = tid>>5, ecol = tid&31)
    const int ecol = tid & 31;
    const int eb   = tid >> 5;
    const int ej   = 32 * jt + ecol;
    float c_bir = 0, c_bhr = 0, c_biz = 0, c_bhz = 0, c_bin = 0, c_bhn = 0, c_wo = 0, bo = 0;
    if (tid < 256) {
        c_bir = bir[ej]; c_bhr = bhr[ej]; c_biz = biz[ej]; c_bhz = bhz[ej];
        c_bin = bin_[ej]; c_bhn = bhn[ej]; c_wo = Wout[ej]; bo = bout[0];
    }

    unsigned* myflag = prog + (size_t)((bg << 5) + jt) * FSTR;
    unsigned* pollp  = prog + (size_t)((bg << 5) + (lane & 31)) * FSTR;
    // bp replica for this waiter: 64B-line r = jt&3 within block-0's page
    unsigned* bprep  = prog + (size_t)(bg << 5) * FSTR + 16 * (jt & 3);

    if (tid < 8) zblk[tid] = 0;
    if (tid < 256) hown[eb][ecol] = h0[(size_t)(b0 + eb) * H_DIM + ej];
    {
        const float* src = x + (size_t)(b0 + wv) * H_DIM + kcol0;
        #pragma unroll
        for (int s = 0; s < 2; ++s) {
            const int c8 = lane + (s << 6);
            if (c8 < CHN) {
                const float4 v0 = *(const float4*)(src + c8 * 8);
                const float4 v1 = *(const float4*)(src + c8 * 8 + 4);
                uint4 o = make_uint4(pack2(v0.x, v0.y), pack2(v0.z, v0.w),
                                     pack2(v1.x, v1.y), pack2(v1.z, v1.w));
                *(uint4*)&axf[wv * APITCH + c8 * 8] = o;
            }
        }
    }

    unsigned cachedf  = 0;    // wave 0: cached dep flags (monotone -> safe)
    unsigned cachedbp = 0;    // wave 0: cached bp replica value

    for (int t = 0; t < T_DIM; ++t) {
        const int slot_r = t & (RING - 1), slot_w = (t + 1) & (RING - 1);

        // ---- poll (wave 0): deps kt>jt at t; backpressure via replicated flag ----
        if (wv == 0) {
            const int kt = lane & 31;
            const int thr = (kt > jt) ? t : -0x40000000;
            if (!__all((int)cachedf >= thr)) {
                for (;;) {
                    cachedf = __hip_atomic_load(pollp, __ATOMIC_RELAXED,
                                                __HIP_MEMORY_SCOPE_AGENT);
                    if (__all((int)cachedf >= thr)) break;
                    __builtin_amdgcn_s_sleep(4);
                }
            }
            if (jt > 0 && (int)cachedbp < t - 31) {
                for (;;) {
                    cachedbp = __hip_atomic_load(bprep, __ATOMIC_RELAXED,
                                                 __HIP_MEMORY_SCOPE_AGENT);
                    if ((int)cachedbp >= t - 31) break;
                    __builtin_amdgcn_s_sleep(32);    // quiet: ~0.9us between re-polls
                }
            }
        }
        __syncthreads();

        // ---- stage h(t): wave wv -> row wv; bypass dwordx4 loads, one wait ----
        {
            const unsigned short* base = hring +
                ((size_t)slot_r * B_DIM + b0 + wv) * H_DIM + kcol0;
            const int cA = lane, cB = lane + 64;
            const bool gA = (cA < CHN), gB = (cB < CHN);
            uint4 o0, o1;
            const unsigned short* a0 = base + cA * 8;
            const unsigned short* a1 = base + cB * 8;
            if (gA) asm volatile("global_load_dwordx4 %0, %1, off sc0 sc1" : "=v"(o0) : "v"(a0));
            if (gB) asm volatile("global_load_dwordx4 %0, %1, off sc0 sc1" : "=v"(o1) : "v"(a1));
            asm volatile("s_waitcnt vmcnt(0)" ::: "memory");
            if (gA) *(uint4*)&ahf[wv * APITCH + cA * 8] = o0;
            if (gB) *(uint4*)&ahf[wv * APITCH + cB * 8] = o1;
        }
        __syncthreads();
        // own-block ring columns are bit-identical to f2bf(hown) (self-published) ✓

        // ---- MFMA: this wave's (jtile, ks slice), 6 gates ----
        f32x4 a0 = 0.f, a1 = 0.f, a2 = 0.f, a3 = 0.f, a4 = 0.f, a5 = 0.f;
        for (int ks = ks_s; ks < ks_e; ++ks) {
            const int off = (ks - jt) * astride;
            const bf16x8 ax = *(const bf16x8*)(pax + off);
            const bf16x8 ah = *(const bf16x8*)(pah + off);
            const unsigned short* pw = pw0 + (size_t)(ks - jt) * 3072;
            const bf16x8 w0 = *(const bf16x8*)(pw);
            const bf16x8 w1 = *(const bf16x8*)(pw + 512);
            const bf16x8 w2 = *(const bf16x8*)(pw + 1024);
            const bf16x8 w3 = *(const bf16x8*)(pw + 1536);
            const bf16x8 w4 = *(const bf16x8*)(pw + 2048);
            const bf16x8 w5 = *(const bf16x8*)(pw + 2560);
            a0 = __builtin_amdgcn_mfma_f32_16x16x32_bf16(ax, w0, a0, 0, 0, 0);
            a1 = __builtin_amdgcn_mfma_f32_16x16x32_bf16(ax, w1, a1, 0, 0, 0);
            a2 = __builtin_amdgcn_mfma_f32_16x16x32_bf16(ax, w2, a2, 0, 0, 0);
            a3 = __builtin_amdgcn_mfma_f32_16x16x32_bf16(ah, w3, a3, 0, 0, 0);
            a4 = __builtin_amdgcn_mfma_f32_16x16x32_bf16(ah, w4, a4, 0, 0, 0);
            a5 = __builtin_amdgcn_mfma_f32_16x16x32_bf16(ah, w5, a5, 0, 0, 0);
        }
        *(f32x4*)&red[wv][0][lane][0] = a0;
        *(f32x4*)&red[wv][1][lane][0] = a1;
        *(f32x4*)&red[wv][2][lane][0] = a2;
        *(f32x4*)&red[wv][3][lane][0] = a3;
        *(f32x4*)&red[wv][4][lane][0] = a4;
        *(f32x4*)&red[wv][5][lane][0] = a5;
        __syncthreads();

        // ---- epilogue: 256 threads = (b 8) x (col 32) ----
        if (tid < 256) {
            const int wb = (ecol >> 4) * 4;
            const int lp = ((eb >> 2) << 4) | (ecol & 15);
            const int rg = eb & 3;
            float s0 = 0, s1 = 0, s2 = 0, s3 = 0, s4 = 0, s5 = 0;
            #pragma unroll
            for (int w2i = 0; w2i < 4; ++w2i) {
                s0 += red[wb + w2i][0][lp][rg]; s1 += red[wb + w2i][1][lp][rg];
                s2 += red[wb + w2i][2][lp][rg]; s3 += red[wb + w2i][3][lp][rg];
                s4 += red[wb + w2i][4][lp][rg]; s5 += red[wb + w2i][5][lp][rg];
            }
            const float xv = x[(size_t)t * B_DIM * H_DIM + (size_t)(b0 + eb) * H_DIM + ej];
            const float hv = hown[eb][ecol];
            const float rp = s0 + c_bir * xv + c_bhr + s3;
            const float zp = s1 + c_biz * xv + c_bhz + s4;
            const float r  = 1.0f / (1.0f + expf(-rp));
            const float z  = 1.0f / (1.0f + expf(-zp));
            const float np = s2 + c_bin * xv + r * (s5 + c_bhn);
            const float n  = tanhf(np);
            const float hnew = hv * z + (1.0f - z) * n;
            hown[eb][ecol] = hnew;
            hb[eb][ecol] = f2bf(hnew);
            float lab = (1.0f / (1.0f + expf(-(hnew * c_wo + bo)))) * xv;
            #pragma unroll
            for (int off = 16; off; off >>= 1)
                lab = fmaxf(lab, __shfl_xor(lab, off));
            if (ecol == 0) pmax[((size_t)t * B_DIM + b0 + eb) * 32 + jt] = lab;
        }
        __syncthreads();   // hb final

        // ---- publish own 8 rows x 32 cols (bf16) to ring slot t+1 ----
        if (tid < 128) {
            const int b = tid >> 4, cq = tid & 15;
            const unsigned val = (unsigned)hb[b][2 * cq] | ((unsigned)hb[b][2 * cq + 1] << 16);
            unsigned* dst = (unsigned*)(hring +
                ((size_t)slot_w * B_DIM + b0 + b) * H_DIM + 32 * jt) + cq;
            __hip_atomic_store(dst, val, __ATOMIC_RELAXED, __HIP_MEMORY_SCOPE_AGENT);
        }
        __syncthreads();   // vmcnt drained before flag release

        // ---- flag release: dep flag (all blocks) + 3 extra bp replicas (block 0) ----
        if (jt == 0) {
            if (tid < 4)
                __hip_atomic_store(myflag + 16 * tid, (unsigned)(t + 1),
                                   __ATOMIC_RELEASE, __HIP_MEMORY_SCOPE_AGENT);
        } else {
            if (tid == 0)
                __hip_atomic_store(myflag, (unsigned)(t + 1),
                                   __ATOMIC_RELEASE, __HIP_MEMORY_SCOPE_AGENT);
        }

        // ---- tail: stage x(t+1) (hides flag propagation + store completion) ----
        if (t < T_DIM - 1) {
            const float* src = x + (size_t)(t + 1) * B_DIM * H_DIM
                             + (size_t)(b0 + wv) * H_DIM + kcol0;
            #pragma unroll
            for (int s = 0; s < 2; ++s) {
                const int c8 = lane + (s << 6);
                if (c8 < CHN) {
                    const float4 v0 = *(const float4*)(src + c8 * 8);
                    const float4 v1 = *(const float4*)(src + c8 * 8 + 4);
                    uint4 o = make_uint4(pack2(v0.x, v0.y), pack2(v0.z, v0.w),
                                         pack2(v1.x, v1.y), pack2(v1.z, v1.w));
                    *(uint4*)&axf[wv * APITCH + c8 * 8] = o;
                }
            }
        }
    }
}

// ---------------- finalize: max over 32 block-maxes, threshold, emit int32 ----------------
__global__ __launch_bounds__(256) void finalize(const float* __restrict__ pmax, int* __restrict__ out)
{
    const int i = blockIdx.x * 256 + threadIdx.x; // 0..T*B-1
    if (i >= T_DIM * B_DIM) return;
    const float4* pm = (const float4*)(pmax + (size_t)i * 32);
    float m = -3.4e38f;
    #pragma unroll
    for (int q = 0; q < 8; ++q) {
        const float4 v = pm[q];
        m = fmaxf(m, fmaxf(fmaxf(v.x, v.y), fmaxf(v.z, v.w)));
    }
    out[i] = (m >= 0.5f) ? 1 : -1;
}

extern "C" void kernel_launch(void* const* d_in, const int* in_sizes, int n_in,
                              void* d_out, int out_size, void* d_ws, size_t ws_size,
                              hipStream_t stream)
{
    const float* x    = (const float*)d_in[0];
    const float* h0   = (const float*)d_in[1];
    const float* W_ir = (const float*)d_in[2];
    const float* W_hr = (const float*)d_in[3];
    const float* W_iz = (const float*)d_in[4];
    const float* W_hz = (const float*)d_in[5];
    const float* W_in = (const float*)d_in[6];
    const float* W_hn = (const float*)d_in[7];
    const float* b_ir = (const float*)d_in[8];
    const float* b_hr = (const float*)d_in[9];
    const float* b_iz = (const float*)d_in[10];
    const float* b_hz = (const float*)d_in[11];
    const float* b_in = (const float*)d_in[12];
    const float* b_hn = (const float*)d_in[13];
    const float* W_out = (const float*)d_in[14];
    const float* b_out = (const float*)d_in[15];

    unsigned short* Wpk   = (unsigned short*)d_ws;                    // ~13 MB
    unsigned short* hring = Wpk + (size_t)NBLK * 2 * KSLOT * 3072;    // 8 MB
    float* pmax = (float*)(hring + (size_t)RING * B_DIM * H_DIM);     // 4 MB
    unsigned* prog = (unsigned*)(pmax + (size_t)T_DIM * B_DIM * 32);  // 1 MB

    prep_pack<<<dim3(NBLK * 64, 6), 128, 0, stream>>>(W_ir, W_iz, W_in, W_hr, W_hz, W_hn, Wpk);
    init_h<<<dim3(288), 256, 0, stream>>>(h0, hring, prog);

    void* args[] = {(void*)&x, (void*)&Wpk,
                    (void*)&b_ir, (void*)&b_hr, (void*)&b_iz, (void*)&b_hz,
                    (void*)&b_in, (void*)&b_hn, (void*)&W_out, (void*)&b_out,
                    (void*)&h0, (void*)&hring, (void*)&pmax, (void*)&prog};
    hipError_t rc = hipLaunchCooperativeKernel((const void*)gru_main, dim3(256), dim3(512),
                                               args, 0, stream);
    (void)rc;

    finalize<<<dim3(T_DIM * B_DIM / 256), 256, 0, stream>>>(pmax, (int*)d_out);
}